// Round 1
// baseline (324.550 us; speedup 1.0000x reference)
//
#include <hip/hip_runtime.h>

// out[b, s1*64+s2, h, e] = RxV[b,h,s2,e] + RxU[b,h,s1,e]
// RxV = W2 @ vm (vm = sum over s1), RxU = W2 @ um (um = sum over s2)
// W2[t][k] = w[h][(t+64-k) mod 127]  (only t=63,k=0 wraps: index 127 -> 0)
//
// Grid: 512 blocks = (b:8, h:16, ec:4 e-chunks of 16), 256 threads.

#define FMA4(acc, s, val)                                                     \
  acc.x += (s) * (val).x; acc.y += (s) * (val).y;                             \
  acc.z += (s) * (val).z; acc.w += (s) * (val).w

__global__ __launch_bounds__(256) void fftbias2d_kernel(
    const float* __restrict__ v,
    const float* __restrict__ w,
    float* __restrict__ out)
{
    __shared__ float  um_w[4][64][16];   // [wave][s1][e_loc] partial um, 16 KB
    __shared__ float4 vm4[64][4];        // [s2][eq]  == vm[s2][e_loc]
    __shared__ float4 um4[64][4];        // [s1][eq]
    __shared__ float4 rxv4[64][4];       // [s2][eq]
    __shared__ float4 rxu4[64][4];       // [s1][eq]
    __shared__ float  w_s[128];          // w_s[127] = w[0] handles the mod wrap

    const int bid   = blockIdx.x;
    const int g     = bid >> 2;          // b*16 + h
    const int ec    = bid & 3;
    const int b     = g >> 4;
    const int h     = g & 15;
    const int t     = threadIdx.x;
    const int lane  = t & 63;
    const int e_loc = t & 15;
    const int sg    = t >> 4;            // 0..15
    const int wv    = t >> 6;            // wave 0..3
    const int e_base = ec << 4;

    // zero per-wave um partials
    float* um_w_flat = &um_w[0][0][0];
#pragma unroll
    for (int i = 0; i < 16; ++i) um_w_flat[t + 256 * i] = 0.0f;
    if (t < 128) w_s[t] = w[h * 127 + (t == 127 ? 0 : t)];
    __syncthreads();

    // ---------------- reduce phase: read v once ----------------
    // v index: b*4194304 + (s1*64+s2)*1024 + h*64 + e
    const float* base = v + (size_t)b * 4194304 + h * 64 + e_base + e_loc
                          + sg * 1024;
    float vmr0 = 0.f, vmr1 = 0.f, vmr2 = 0.f, vmr3 = 0.f;

    for (int s1 = 0; s1 < 64; s1 += 2) {
        const float* p0 = base + s1 * 65536;
        const float* p1 = p0 + 65536;
        float a0 = p0[0], a1 = p0[16384], a2 = p0[32768], a3 = p0[49152];
        float b0 = p1[0], b1 = p1[16384], b2 = p1[32768], b3 = p1[49152];
        vmr0 += a0 + b0; vmr1 += a1 + b1; vmr2 += a2 + b2; vmr3 += a3 + b3;
        float sA = (a0 + a1) + (a2 + a3);
        float sB = (b0 + b1) + (b2 + b3);
        // sum over the 4 sg values resident in this wave (lane bits 4,5)
        sA += __shfl_xor(sA, 16); sA += __shfl_xor(sA, 32);
        sB += __shfl_xor(sB, 16); sB += __shfl_xor(sB, 32);
        if (lane < 16) {
            um_w[wv][s1][e_loc]     += sA;
            um_w[wv][s1 + 1][e_loc] += sB;
        }
    }
    __syncthreads();

    // vm registers -> LDS (thread uniquely owns (e_loc, s2=sg+16c))
    float* vm_f = (float*)vm4;
    vm_f[(sg     ) * 16 + e_loc] = vmr0;
    vm_f[(sg + 16) * 16 + e_loc] = vmr1;
    vm_f[(sg + 32) * 16 + e_loc] = vmr2;
    vm_f[(sg + 48) * 16 + e_loc] = vmr3;
    // reduce um over the 4 waves
    float* um_f = (float*)um4;
#pragma unroll
    for (int i = 0; i < 4; ++i) {
        int idx = t + 256 * i;   // s1*16 + e_loc
        um_f[idx] = um_w_flat[idx] + um_w_flat[1024 + idx]
                  + um_w_flat[2048 + idx] + um_w_flat[3072 + idx];
    }
    __syncthreads();

    // ---------------- matvec phase: 1 wave, 4tt x 4e x {V,U} tiles ----------
    if (t < 64) {
        const int eq = t & 3;
        const int T0 = t & ~3;           // (t>>2)*4: tt block base 0..60
        float4 aV0 = {0,0,0,0}, aV1 = {0,0,0,0}, aV2 = {0,0,0,0}, aV3 = {0,0,0,0};
        float4 aU0 = {0,0,0,0}, aU1 = {0,0,0,0}, aU2 = {0,0,0,0}, aU3 = {0,0,0,0};
        // rolling window: at iter k, Wj = w_s[T0+64-k+j]
        float W0 = w_s[T0 + 64], W1 = w_s[T0 + 65];
        float W2v = w_s[T0 + 66], W3v = w_s[T0 + 67];
        for (int k = 0; k < 64; ++k) {
            float4 vmv = vm4[k][eq];
            float4 umv = um4[k][eq];
            FMA4(aV0, W0, vmv);  FMA4(aU0, W0, umv);
            FMA4(aV1, W1, vmv);  FMA4(aU1, W1, umv);
            FMA4(aV2, W2v, vmv); FMA4(aU2, W2v, umv);
            FMA4(aV3, W3v, vmv); FMA4(aU3, W3v, umv);
            if (k < 63) {
                float nw = w_s[T0 + 63 - k];
                W3v = W2v; W2v = W1; W1 = W0; W0 = nw;
            }
        }
        rxv4[T0 + 0][eq] = aV0; rxv4[T0 + 1][eq] = aV1;
        rxv4[T0 + 2][eq] = aV2; rxv4[T0 + 3][eq] = aV3;
        rxu4[T0 + 0][eq] = aU0; rxu4[T0 + 1][eq] = aU1;
        rxu4[T0 + 2][eq] = aU2; rxu4[T0 + 3][eq] = aU3;
    }
    __syncthreads();

    // ---------------- write phase: out = RxV[s2] + RxU[s1] ----------------
    {
        const int e4 = t & 3;        // float4 slot within e-chunk
        const int s2 = t >> 2;       // 0..63
        float4 rvv = rxv4[s2][e4];   // fixed for this thread
        float* outp = out + (size_t)b * 4194304 + h * 64 + e_base + e4 * 4
                          + s2 * 1024;
#pragma unroll 4
        for (int s1 = 0; s1 < 64; ++s1) {
            float4 ruv = rxu4[s1][e4];
            float4 r;
            r.x = rvv.x + ruv.x; r.y = rvv.y + ruv.y;
            r.z = rvv.z + ruv.z; r.w = rvv.w + ruv.w;
            *(float4*)(outp + (size_t)s1 * 65536) = r;
        }
    }
}

extern "C" void kernel_launch(void* const* d_in, const int* in_sizes, int n_in,
                              void* d_out, int out_size, void* d_ws, size_t ws_size,
                              hipStream_t stream) {
    const float* v = (const float*)d_in[0];   // [8, 4096, 16, 64] fp32
    const float* w = (const float*)d_in[1];   // [1, 16, 127] fp32
    float* out = (float*)d_out;               // [8, 4096, 16, 64] fp32
    fftbias2d_kernel<<<512, 256, 0, stream>>>(v, w, out);
}

// Round 2
// 257.666 us; speedup vs baseline: 1.2596x; 1.2596x over previous
//
#include <hip/hip_runtime.h>

// Decomposition (round-1 semantics, verified passing):
//   um[b,h,s1,e] = sum_s2 v[b, s1*64+s2, h, e]
//   vm[b,h,s2,e] = sum_s1 v[b, s1*64+s2, h, e]
//   RxV = W2 @ vm, RxU = W2 @ um,  W2[t][k] = w[h][(t+64-k) mod 127]
//   out[b, s1*64+s2, h, e] = RxV[s2] + RxU[s1]
//
// ws layout (float4 units):
//   vm_part[slice 4][b 8][s2 64][he4 256]  @ 0        (524288 f4, 8.4 MB)
//   um     [b 8][s1 64][he4 256]           @ 524288   (131072 f4)
//   RxV    [b 8][h 16][s2 64][e4 16]       @ 655360   (131072 f4)
//   RxU    [b 8][h 16][s1 64][e4 16]       @ 786432   (131072 f4)

#define FMA4(acc, s, val)                                                     \
  acc.x += (s) * (val).x; acc.y += (s) * (val).y;                             \
  acc.z += (s) * (val).z; acc.w += (s) * (val).w

#define ADD4(acc, a)                                                          \
  acc.x += (a).x; acc.y += (a).y; acc.z += (a).z; acc.w += (a).w

// ---------------- K1: reduction pass (reads v once) ----------------
// grid 1024 = (b:8, slice:4, hcb:32), 256 threads = (rowth:32, slot:8)
__global__ __launch_bounds__(256, 4) void k1_reduce(
    const float4* __restrict__ v4,
    float4* __restrict__ vm_part,
    float4* __restrict__ um_ws)
{
    __shared__ float4 um_w[4][16][8];    // [wave][s1l][slot], 8 KB

    const int bid   = blockIdx.x;
    const int hcb   = bid & 31;
    const int slice = (bid >> 5) & 3;
    const int b     = bid >> 7;
    const int t     = threadIdx.x;
    const int slot  = t & 7;
    const int rowth = t >> 3;            // 0..31  (s2 = rowth, rowth+32)
    const int wv    = t >> 6;
    const int he4   = hcb * 8 + slot;    // 0..255

    const float4* base = v4 + ((size_t)(b * 4096 + slice * 1024 + rowth) * 256 + he4);

    float4 um_acc[16];
#pragma unroll
    for (int j = 0; j < 16; ++j) um_acc[j] = make_float4(0.f, 0.f, 0.f, 0.f);
    float4 vm0 = make_float4(0.f, 0.f, 0.f, 0.f);
    float4 vm1 = make_float4(0.f, 0.f, 0.f, 0.f);

#pragma unroll
    for (int s1l = 0; s1l < 16; ++s1l) {
        float4 a  = base[s1l * 16384];          // s2 = rowth
        float4 b4 = base[s1l * 16384 + 8192];   // s2 = rowth + 32
        ADD4(um_acc[s1l], a); ADD4(um_acc[s1l], b4);
        ADD4(vm0, a); ADD4(vm1, b4);
    }

    // vm: thread-local complete over this slice -> direct store
    vm_part[((size_t)(slice * 8 + b) * 64 + rowth) * 256 + he4]        = vm0;
    vm_part[((size_t)(slice * 8 + b) * 64 + rowth + 32) * 256 + he4]   = vm1;

    // um: reduce over rowth (lane bits 3,4,5 within wave), then 4 waves via LDS
#pragma unroll
    for (int j = 0; j < 16; ++j) {
        float4 s = um_acc[j];
        s.x += __shfl_xor(s.x, 8);  s.y += __shfl_xor(s.y, 8);
        s.z += __shfl_xor(s.z, 8);  s.w += __shfl_xor(s.w, 8);
        s.x += __shfl_xor(s.x, 16); s.y += __shfl_xor(s.y, 16);
        s.z += __shfl_xor(s.z, 16); s.w += __shfl_xor(s.w, 16);
        s.x += __shfl_xor(s.x, 32); s.y += __shfl_xor(s.y, 32);
        s.z += __shfl_xor(s.z, 32); s.w += __shfl_xor(s.w, 32);
        if ((t & 63) < 8) um_w[wv][j][slot] = s;
    }
    __syncthreads();

    if (t < 128) {
        const int s1l = t >> 3;
        const int sl2 = t & 7;
        float4 s = um_w[0][s1l][sl2];
        ADD4(s, um_w[1][s1l][sl2]);
        ADD4(s, um_w[2][s1l][sl2]);
        ADD4(s, um_w[3][s1l][sl2]);
        um_ws[((size_t)b * 64 + slice * 16 + s1l) * 256 + hcb * 8 + sl2] = s;
    }
}

// ---------------- K2: slice-reduce + dual matvec ----------------
// grid 128 = (b:8, h:16), 256 threads
__global__ __launch_bounds__(256) void k2_matvec(
    const float4* __restrict__ vm_part,
    const float4* __restrict__ um_ws,
    const float*  __restrict__ w,
    float4* __restrict__ rxv,
    float4* __restrict__ rxu)
{
    __shared__ float4 vm_s[64][16];
    __shared__ float4 um_s[64][16];
    __shared__ float  w_s[128];          // w_s[127] = w[0] (mod-127 wrap)

    const int bid = blockIdx.x;
    const int h   = bid & 15;
    const int b   = bid >> 4;
    const int t   = threadIdx.x;

    if (t < 128) w_s[t] = w[h * 127 + (t == 127 ? 0 : t)];

    {
        const int e4 = t & 15;
        const int sg = t >> 4;
#pragma unroll
        for (int r = 0; r < 4; ++r) {
            const int s2 = sg + 16 * r;
            float4 acc = vm_part[((size_t)(0 * 8 + b) * 64 + s2) * 256 + h * 16 + e4];
            ADD4(acc, vm_part[((size_t)(1 * 8 + b) * 64 + s2) * 256 + h * 16 + e4]);
            ADD4(acc, vm_part[((size_t)(2 * 8 + b) * 64 + s2) * 256 + h * 16 + e4]);
            ADD4(acc, vm_part[((size_t)(3 * 8 + b) * 64 + s2) * 256 + h * 16 + e4]);
            vm_s[s2][e4] = acc;
            um_s[s2][e4] = um_ws[((size_t)b * 64 + s2) * 256 + h * 16 + e4];
        }
    }
    __syncthreads();

    {
        const int e4 = t & 15;
        const int T0 = (t >> 4) * 4;     // 0,4,...,60
        float4 aV0 = {0,0,0,0}, aV1 = {0,0,0,0}, aV2 = {0,0,0,0}, aV3 = {0,0,0,0};
        float4 aU0 = {0,0,0,0}, aU1 = {0,0,0,0}, aU2 = {0,0,0,0}, aU3 = {0,0,0,0};
        float W0 = w_s[T0 + 64], W1 = w_s[T0 + 65];
        float W2v = w_s[T0 + 66], W3v = w_s[T0 + 67];
        for (int k = 0; k < 64; ++k) {
            float4 vmv = vm_s[k][e4];
            float4 umv = um_s[k][e4];
            FMA4(aV0, W0, vmv);  FMA4(aU0, W0, umv);
            FMA4(aV1, W1, vmv);  FMA4(aU1, W1, umv);
            FMA4(aV2, W2v, vmv); FMA4(aU2, W2v, umv);
            FMA4(aV3, W3v, vmv); FMA4(aU3, W3v, umv);
            if (k < 63) {
                float nw = w_s[T0 + 63 - k];
                W3v = W2v; W2v = W1; W1 = W0; W0 = nw;
            }
        }
        const size_t o = (size_t)(b * 16 + h) * 64 * 16 + e4;
        rxv[o + (T0 + 0) * 16] = aV0; rxv[o + (T0 + 1) * 16] = aV1;
        rxv[o + (T0 + 2) * 16] = aV2; rxv[o + (T0 + 3) * 16] = aV3;
        rxu[o + (T0 + 0) * 16] = aU0; rxu[o + (T0 + 1) * 16] = aU1;
        rxu[o + (T0 + 2) * 16] = aU2; rxu[o + (T0 + 3) * 16] = aU3;
    }
}

// ---------------- K3: broadcast write ----------------
// grid 8192, 256 threads; block writes 4 consecutive 4-KB s-rows
__global__ __launch_bounds__(256) void k3_write(
    const float4* __restrict__ rxv,
    const float4* __restrict__ rxu,
    float4* __restrict__ out4)
{
    const int bid  = blockIdx.x;
    const int t    = threadIdx.x;
    const int sidb = bid * 4;            // 4 consecutive s indices
    const int b    = sidb >> 12;
    const int s1   = (sidb >> 6) & 63;
    const int s2b  = sidb & 63;          // s2b..s2b+3 (never crosses 64)
    const int h    = t >> 4;
    const int e4   = t & 15;

    const size_t g  = (size_t)(b * 16 + h) * 64;
    const float4 ru = rxu[(g + s1) * 16 + e4];
    float4* outp = out4 + ((size_t)(b * 4096 + s1 * 64 + s2b) * 256 + t);

#pragma unroll
    for (int r = 0; r < 4; ++r) {
        float4 rv = rxv[(g + s2b + r) * 16 + e4];
        float4 o;
        o.x = ru.x + rv.x; o.y = ru.y + rv.y;
        o.z = ru.z + rv.z; o.w = ru.w + rv.w;
        outp[r * 256] = o;
    }
}

extern "C" void kernel_launch(void* const* d_in, const int* in_sizes, int n_in,
                              void* d_out, int out_size, void* d_ws, size_t ws_size,
                              hipStream_t stream) {
    const float4* v4 = (const float4*)d_in[0];  // [8, 4096, 16, 64] fp32
    const float*  w  = (const float*)d_in[1];   // [1, 16, 127] fp32
    float4* out4 = (float4*)d_out;              // [8, 4096, 16, 64] fp32

    float4* ws4     = (float4*)d_ws;
    float4* vm_part = ws4;                      // 524288 f4
    float4* um_ws   = ws4 + 524288;             // 131072 f4
    float4* rxv     = ws4 + 655360;             // 131072 f4
    float4* rxu     = ws4 + 786432;             // 131072 f4 (total 14.7 MB)

    k1_reduce<<<1024, 256, 0, stream>>>(v4, vm_part, um_ws);
    k2_matvec<<<128, 256, 0, stream>>>(vm_part, um_ws, w, rxv, rxu);
    k3_write<<<8192, 256, 0, stream>>>(rxv, rxu, out4);
}

// Round 3
// 242.922 us; speedup vs baseline: 1.3360x; 1.0607x over previous
//
#include <hip/hip_runtime.h>

// Decomposition (verified passing, rounds 1-2):
//   um[b,h,s1,e] = sum_s2 v[b, s1*64+s2, h, e]
//   vm[b,h,s2,e] = sum_s1 v[b, s1*64+s2, h, e]
//   RxV = W2 @ vm, RxU = W2 @ um,  W2[t][k] = w[h][(t+64-k) mod 127]
//   out[b, s1*64+s2, h, e] = RxV[s2] + RxU[s1]
//
// ws layout (f4 = float-x4 units):
//   vm_part[slice 4][b 8][s2 64][he4 256]  @ 0        (524288 f4, 8.4 MB)
//   um     [b 8][s1 64][he4 256]           @ 524288   (131072 f4)
//   RxV    [b 8][h 16][s2 64][e4 16]       @ 655360   (131072 f4)
//   RxU    [b 8][h 16][s1 64][e4 16]       @ 786432   (131072 f4)

typedef float f4 __attribute__((ext_vector_type(4)));

// ---------------- K1: reduction pass (reads v once, nontemporal) ----------
// grid 1024 = (b:8, slice:4, hcb:32), 256 threads = (rowth:32, slot:8)
__global__ __launch_bounds__(256, 4) void k1_reduce(
    const f4* __restrict__ v4,
    f4* __restrict__ vm_part,
    f4* __restrict__ um_ws)
{
    __shared__ f4 um_w[4][16][8];        // [wave][s1l][slot], 8 KB

    const int bid   = blockIdx.x;
    const int hcb   = bid & 31;
    const int slice = (bid >> 5) & 3;
    const int b     = bid >> 7;
    const int t     = threadIdx.x;
    const int slot  = t & 7;
    const int rowth = t >> 3;            // 0..31  (s2 = rowth, rowth+32)
    const int wv    = t >> 6;
    const int he4   = hcb * 8 + slot;    // 0..255

    const f4* base = v4 + ((size_t)(b * 4096 + slice * 1024 + rowth) * 256 + he4);

    f4 um_acc[16];
#pragma unroll
    for (int j = 0; j < 16; ++j) um_acc[j] = (f4)0.f;
    f4 vm0 = (f4)0.f, vm1 = (f4)0.f;

#pragma unroll
    for (int s1l = 0; s1l < 16; ++s1l) {
        f4 a  = __builtin_nontemporal_load(base + s1l * 16384);          // s2 = rowth
        f4 b4 = __builtin_nontemporal_load(base + s1l * 16384 + 8192);   // s2 = rowth+32
        um_acc[s1l] += a + b4;
        vm0 += a;
        vm1 += b4;
    }

    // vm: thread-local complete over this slice -> direct store (cached; K2 rereads)
    vm_part[((size_t)(slice * 8 + b) * 64 + rowth) * 256 + he4]      = vm0;
    vm_part[((size_t)(slice * 8 + b) * 64 + rowth + 32) * 256 + he4] = vm1;

    // um: reduce over rowth (lane bits 3,4,5 within wave), then 4 waves via LDS
#pragma unroll
    for (int j = 0; j < 16; ++j) {
        f4 s = um_acc[j];
        s.x += __shfl_xor(s.x, 8);  s.y += __shfl_xor(s.y, 8);
        s.z += __shfl_xor(s.z, 8);  s.w += __shfl_xor(s.w, 8);
        s.x += __shfl_xor(s.x, 16); s.y += __shfl_xor(s.y, 16);
        s.z += __shfl_xor(s.z, 16); s.w += __shfl_xor(s.w, 16);
        s.x += __shfl_xor(s.x, 32); s.y += __shfl_xor(s.y, 32);
        s.z += __shfl_xor(s.z, 32); s.w += __shfl_xor(s.w, 32);
        if ((t & 63) < 8) um_w[wv][j][slot] = s;
    }
    __syncthreads();

    if (t < 128) {
        const int s1l = t >> 3;
        const int sl2 = t & 7;
        f4 s = um_w[0][s1l][sl2] + um_w[1][s1l][sl2]
             + um_w[2][s1l][sl2] + um_w[3][s1l][sl2];
        um_ws[((size_t)b * 64 + slice * 16 + s1l) * 256 + hcb * 8 + sl2] = s;
    }
}

// ---------------- K2: slice-reduce + dual matvec ----------------
// grid 128 = (b:8, h:16), 256 threads
__global__ __launch_bounds__(256) void k2_matvec(
    const f4* __restrict__ vm_part,
    const f4* __restrict__ um_ws,
    const float* __restrict__ w,
    f4* __restrict__ rxv,
    f4* __restrict__ rxu)
{
    __shared__ f4 vm_s[64][16];
    __shared__ f4 um_s[64][16];
    __shared__ float w_s[128];           // w_s[127] = w[0] (mod-127 wrap)

    const int bid = blockIdx.x;
    const int h   = bid & 15;
    const int b   = bid >> 4;
    const int t   = threadIdx.x;

    if (t < 128) w_s[t] = w[h * 127 + (t == 127 ? 0 : t)];

    {
        const int e4 = t & 15;
        const int sg = t >> 4;
#pragma unroll
        for (int r = 0; r < 4; ++r) {
            const int s2 = sg + 16 * r;
            f4 acc = vm_part[((size_t)(0 * 8 + b) * 64 + s2) * 256 + h * 16 + e4]
                   + vm_part[((size_t)(1 * 8 + b) * 64 + s2) * 256 + h * 16 + e4]
                   + vm_part[((size_t)(2 * 8 + b) * 64 + s2) * 256 + h * 16 + e4]
                   + vm_part[((size_t)(3 * 8 + b) * 64 + s2) * 256 + h * 16 + e4];
            vm_s[s2][e4] = acc;
            um_s[s2][e4] = um_ws[((size_t)b * 64 + s2) * 256 + h * 16 + e4];
        }
    }
    __syncthreads();

    {
        const int e4 = t & 15;
        const int T0 = (t >> 4) * 4;     // 0,4,...,60
        f4 aV0 = (f4)0.f, aV1 = (f4)0.f, aV2 = (f4)0.f, aV3 = (f4)0.f;
        f4 aU0 = (f4)0.f, aU1 = (f4)0.f, aU2 = (f4)0.f, aU3 = (f4)0.f;
        float W0 = w_s[T0 + 64], W1 = w_s[T0 + 65];
        float W2v = w_s[T0 + 66], W3v = w_s[T0 + 67];
        for (int k = 0; k < 64; ++k) {
            f4 vmv = vm_s[k][e4];
            f4 umv = um_s[k][e4];
            aV0 += W0 * vmv;  aU0 += W0 * umv;
            aV1 += W1 * vmv;  aU1 += W1 * umv;
            aV2 += W2v * vmv; aU2 += W2v * umv;
            aV3 += W3v * vmv; aU3 += W3v * umv;
            if (k < 63) {
                float nw = w_s[T0 + 63 - k];
                W3v = W2v; W2v = W1; W1 = W0; W0 = nw;
            }
        }
        const size_t o = (size_t)(b * 16 + h) * 64 * 16 + e4;
        rxv[o + (T0 + 0) * 16] = aV0; rxv[o + (T0 + 1) * 16] = aV1;
        rxv[o + (T0 + 2) * 16] = aV2; rxv[o + (T0 + 3) * 16] = aV3;
        rxu[o + (T0 + 0) * 16] = aU0; rxu[o + (T0 + 1) * 16] = aU1;
        rxu[o + (T0 + 2) * 16] = aU2; rxu[o + (T0 + 3) * 16] = aU3;
    }
}

// ---------------- K3: broadcast write (nontemporal stores) ----------------
// grid 8192, 256 threads; block writes 4 consecutive 4-KB s-rows
__global__ __launch_bounds__(256) void k3_write(
    const f4* __restrict__ rxv,
    const f4* __restrict__ rxu,
    f4* __restrict__ out4)
{
    const int bid  = blockIdx.x;
    const int t    = threadIdx.x;
    const int sidb = bid * 4;            // 4 consecutive s indices
    const int b    = sidb >> 12;
    const int s1   = (sidb >> 6) & 63;
    const int s2b  = sidb & 63;          // s2b..s2b+3 (never crosses 64)
    const int h    = t >> 4;
    const int e4   = t & 15;

    const size_t g = (size_t)(b * 16 + h) * 64;
    const f4 ru = rxu[(g + s1) * 16 + e4];
    f4* outp = out4 + ((size_t)(b * 4096 + s1 * 64 + s2b) * 256 + t);

#pragma unroll
    for (int r = 0; r < 4; ++r) {
        f4 rv = rxv[(g + s2b + r) * 16 + e4];
        __builtin_nontemporal_store(ru + rv, outp + r * 256);
    }
}

extern "C" void kernel_launch(void* const* d_in, const int* in_sizes, int n_in,
                              void* d_out, int out_size, void* d_ws, size_t ws_size,
                              hipStream_t stream) {
    const f4*    v4 = (const f4*)d_in[0];     // [8, 4096, 16, 64] fp32
    const float* w  = (const float*)d_in[1];  // [1, 16, 127] fp32
    f4* out4 = (f4*)d_out;                    // [8, 4096, 16, 64] fp32

    f4* ws4     = (f4*)d_ws;
    f4* vm_part = ws4;                        // 524288 f4
    f4* um_ws   = ws4 + 524288;               // 131072 f4
    f4* rxv     = ws4 + 655360;               // 131072 f4
    f4* rxu     = ws4 + 786432;               // 131072 f4 (total 14.7 MB)

    k1_reduce<<<1024, 256, 0, stream>>>(v4, vm_part, um_ws);
    k2_matvec<<<128, 256, 0, stream>>>(vm_part, um_ws, w, rxv, rxu);
    k3_write<<<8192, 256, 0, stream>>>(rxv, rxu, out4);
}